// Round 10
// baseline (148.376 us; speedup 1.0000x reference)
//
#include <hip/hip_runtime.h>
#include <hip/hip_bf16.h>
#include <math.h>

#define L_SEQ 1024
#define BSZ 8
#define EMB 512
#define NH 8
#define DQ 64
#define BH 64          // BSZ*NH
#define NQKV 1536      // 3*NH*DQ

// Q is pre-scaled by (emb_dim/n_head)^-0.5 * log2(e) so that
// softmax numerator = exp2(mfma_score) with zero extra VALU per element.
#define SCALE_Q 0.18033688f

typedef __attribute__((ext_vector_type(8))) short short8;   // 8 bf16 = 4 VGPR
typedef __attribute__((ext_vector_type(4))) float f32x4;

#define GPTR(x) ((const __attribute__((address_space(1))) void*)(x))
#define LPTR(x) ((__attribute__((address_space(3))) void*)(x))

__device__ __forceinline__ unsigned short bf16u(float x) {
  __hip_bfloat16 h = __float2bfloat16(x);
  return *(unsigned short*)&h;
}

// ---------------------------------------------------------------------------
// Kernel 0: f32 -> bf16 convert of emb (8192x512) and W (1536x512).
// ---------------------------------------------------------------------------
__global__ __launch_bounds__(256) void to_bf16(
    const float* __restrict__ emb, const float* __restrict__ W,
    unsigned short* __restrict__ embB, unsigned short* __restrict__ WB) {
  const size_t t = (size_t)blockIdx.x * 256 + threadIdx.x;
  size_t base = t * 8;
  const float* src;
  unsigned short* dst;
  size_t off;
  if (base < (size_t)8192 * 512) { src = emb; dst = embB; off = base; }
  else { src = W; dst = WB; off = base - (size_t)8192 * 512; }
  float4 v0 = *(const float4*)&src[off];
  float4 v1 = *(const float4*)&src[off + 4];
  short8 o;
  o[0] = bf16u(v0.x); o[1] = bf16u(v0.y); o[2] = bf16u(v0.z); o[3] = bf16u(v0.w);
  o[4] = bf16u(v1.x); o[5] = bf16u(v1.y); o[6] = bf16u(v1.z); o[7] = bf16u(v1.w);
  *(short8*)&dst[off] = o;
}

// ---------------------------------------------------------------------------
// Kernel A: QKV projection, bf16 MFMA (m97 pattern). Q gets SCALE_Q folded in.
// Epilogue: C-tile staged to LDS (Cs[128][132] bf16), then each 64-col
// half-tile is a contiguous [bh][l][0..63] run -> short8 coalesced stores.
// ---------------------------------------------------------------------------
__global__ __launch_bounds__(256) void qkv_mfma(
    const unsigned short* __restrict__ A,   // embB [8192][512]
    const unsigned short* __restrict__ B,   // WB   [1536][512]
    const float* __restrict__ bias,
    unsigned short* __restrict__ Qb, unsigned short* __restrict__ Kb,
    unsigned short* __restrict__ Vb) {
  __shared__ __align__(16) unsigned short As[128][32];  // 8 KB, unpadded
  __shared__ __align__(16) unsigned short Bs[128][32];  // 8 KB
  __shared__ __align__(16) unsigned short Cs[128][132]; // 33 KB, +4 pad
  const int tid = threadIdx.x;
  const int wave = tid >> 6, lane = tid & 63;
  const int quad = lane >> 4, col = lane & 15;
  const int wr = wave >> 1, wc = wave & 1;
  const int m0 = blockIdx.y * 128, n0 = blockIdx.x * 128;
  const int r16 = lane >> 2, q4 = lane & 3;

  f32x4 acc[4][4] = {};

  for (int kt = 0; kt < EMB; kt += 32) {
    __syncthreads();
#pragma unroll
    for (int c = 0; c < 2; ++c) {
      const int rowA = (c * 4 + wave) * 16;
      __builtin_amdgcn_global_load_lds(
          GPTR(A + (size_t)(m0 + rowA + r16) * EMB + kt + q4 * 8),
          LPTR(&As[rowA][0]), 16, 0, 0);
      __builtin_amdgcn_global_load_lds(
          GPTR(B + (size_t)(n0 + rowA + r16) * EMB + kt + q4 * 8),
          LPTR(&Bs[rowA][0]), 16, 0, 0);
    }
    __syncthreads();
    short8 af[4], bf[4];
#pragma unroll
    for (int i = 0; i < 4; ++i)
      af[i] = *(const short8*)&As[wr * 64 + i * 16 + col][quad * 8];
#pragma unroll
    for (int j = 0; j < 4; ++j)
      bf[j] = *(const short8*)&Bs[wc * 64 + j * 16 + col][quad * 8];
#pragma unroll
    for (int i = 0; i < 4; ++i)
#pragma unroll
      for (int j = 0; j < 4; ++j)
        acc[i][j] =
            __builtin_amdgcn_mfma_f32_16x16x32_bf16(af[i], bf[j], acc[i][j],
                                                    0, 0, 0);
  }

#pragma unroll
  for (int j = 0; j < 4; ++j) {
    const int n = wc * 64 + j * 16 + col;     // tile col 0..127
    const float bj = bias[n0 + n];
    const bool isQ = (((n0 + n) >> 6) % 3) == 0;
#pragma unroll
    for (int i = 0; i < 4; ++i) {
      const int mrow = wr * 64 + i * 16 + quad * 4;
#pragma unroll
      for (int r = 0; r < 4; ++r) {
        float val = acc[i][j][r] + bj;
        if (isQ) val *= SCALE_Q;
        Cs[mrow + r][n] = bf16u(val);
      }
    }
  }
  __syncthreads();
  const int bb = lane >> 3, oct = lane & 7;
#pragma unroll
  for (int e = 0; e < 8; ++e) {
    const int idx = wave * 8 + e;
    const int half = idx >> 4, l = idx & 15;
    const int G = (n0 >> 6) + half;       // 64-col block id, 0..23
    const int h = G / 3, sel = G % 3;
    unsigned short* dst = (sel == 0) ? Qb : (sel == 1) ? Kb : Vb;
    short8 v = *(const short8*)&Cs[l * 8 + bb][half * 64 + oct * 8];
    const int lglob = (m0 >> 3) + l;
    *(short8*)&dst[(((size_t)(bb * NH + h)) * L_SEQ + lglob) * DQ + oct * 8] = v;
  }
}

// ---------------------------------------------------------------------------
// Kernel B1: invz[bh][l] = 1 / sum_m exp2(s_lm).
// v4: grid 1024 = (bh = blk&63, qc = blk>>6 in 0..15), 64 q-rows per block,
// wave owns 16 rows -> 4 blocks/CU, 16 waves/CU (latency hiding was the
// bottleneck at 2 blk/CU). Double-buffered LDS; prefetch issued AFTER the
// barrier so the compiler's vmcnt(0) drain at s_barrier does NOT wait on it
// (R9 had it before the barrier -> overlap defeated). Loads stay in flight
// through the full compute section, consumed at next iter's LDS write.
// Dbuf safety: readers of buf b at iter kt vs overwrite at iter kt+2 are
// separated by barrier(kt+1). Also zero-inits Oacc/cnt for attn_aw.
// ---------------------------------------------------------------------------
__global__ __launch_bounds__(256) void attn_z(
    const unsigned short* __restrict__ Qb, const unsigned short* __restrict__ Kb,
    float* __restrict__ invz, float* __restrict__ Oacc, int* __restrict__ cnt) {
  const int bh = blockIdx.x & 63;   // blk%8 = bh%8 -> same-bh blocks same XCD
  const int qc = blockIdx.x >> 6;   // 0..15, 64 rows each
  const int tid = threadIdx.x;
  const int wave = tid >> 6, lane = tid & 63;
  const int quad = lane >> 4, col = lane & 15;

  __shared__ __align__(16) unsigned short Ks[2][64][72];  // 18 KB

  if (qc == 0) {
    if (tid < 64) Oacc[(size_t)bh * 64 + tid] = 0.f;
    if (tid == 0) cnt[bh] = 0;
  }

  const unsigned short* kbase = &Kb[(size_t)bh * L_SEQ * DQ];

  // Q fragments for this wave's 16 rows
  const unsigned short* qp =
      &Qb[((size_t)bh * L_SEQ + qc * 64 + wave * 16 + col) * DQ];
  short8 qa0 = *(const short8*)&qp[quad * 8];
  short8 qa1 = *(const short8*)&qp[32 + quad * 8];

  const int sr = tid >> 2;         // staging row 0..63
  const int so = (tid & 3) * 16;   // staging col offset (shorts)

  float zacc[4] = {0.f, 0.f, 0.f, 0.f};

  short8 st0, st1;
  {  // prefetch tile 0
    const unsigned short* s8 = kbase + (size_t)sr * DQ + so;
    st0 = *(const short8*)s8;
    st1 = *(const short8*)(s8 + 8);
  }

#pragma unroll 2
  for (int kt = 0; kt < 16; ++kt) {
    const int buf = kt & 1;
    *(short8*)&Ks[buf][sr][so] = st0;
    *(short8*)&Ks[buf][sr][so + 8] = st1;
    __syncthreads();
    if (kt + 1 < 16) {  // prefetch AFTER barrier: stays in flight in compute
      const unsigned short* s8 =
          kbase + ((size_t)((kt + 1) * 64 + sr)) * DQ + so;
      st0 = *(const short8*)s8;
      st1 = *(const short8*)(s8 + 8);
    }
#pragma unroll
    for (int sub = 0; sub < 4; ++sub) {
      const unsigned short* kp = &Ks[buf][sub * 16 + col][0];
      short8 kb0 = *(const short8*)&kp[quad * 8];
      short8 kb1 = *(const short8*)&kp[32 + quad * 8];
      f32x4 s = {0.f, 0.f, 0.f, 0.f};
      s = __builtin_amdgcn_mfma_f32_16x16x32_bf16(qa0, kb0, s, 0, 0, 0);
      s = __builtin_amdgcn_mfma_f32_16x16x32_bf16(qa1, kb1, s, 0, 0, 0);
#pragma unroll
      for (int j = 0; j < 4; ++j) zacc[j] += __builtin_amdgcn_exp2f(s[j]);
    }
  }
  float* dst = &invz[(size_t)bh * L_SEQ + qc * 64];
#pragma unroll
  for (int j = 0; j < 4; ++j) {
    float z = zacc[j];
#pragma unroll
    for (int off = 1; off <= 8; off <<= 1) z += __shfl_xor(z, off, 64);
    if (col == j)
      dst[wave * 16 + quad * 4 + j] = __builtin_amdgcn_rcpf(z);
  }
}

// ---------------------------------------------------------------------------
// Kernel B2 (fused): grid 1024 = (bh, kc in 0..15), 64 keys per block, wave
// owns 16 keys (K rows as A-operand). Q tiles double-buffered with
// post-barrier prefetch (as B1). After the sweep: aw for this block's 64
// keys -> LDS, local V-combine (disjoint 8 KB of V), atomicAdd into
// Oacc[bh], 16th block per bh does GroupNorm + out (G16-safe: device-scope
// atomics + threadfence release/acquire).
// ---------------------------------------------------------------------------
__global__ __launch_bounds__(256) void attn_aw(
    const unsigned short* __restrict__ Qb, const unsigned short* __restrict__ Kb,
    const unsigned short* __restrict__ Vb, const float* __restrict__ invz,
    const float* __restrict__ gnw, const float* __restrict__ gnb,
    float* __restrict__ Oacc, int* __restrict__ cnt, float* __restrict__ out) {
  const int bh = blockIdx.x & 63;
  const int kc = blockIdx.x >> 6;   // 0..15, 64 keys each
  const int tid = threadIdx.x;
  const int wave = tid >> 6, lane = tid & 63;
  const int quad = lane >> 4, col = lane & 15;

  __shared__ __align__(16) unsigned short Qs[2][64][72];  // 18 KB
  __shared__ float izs[1024];                             // 4 KB
  __shared__ float aws[64];
  __shared__ float red[4][64];
  __shared__ int lastFlag;

  const unsigned short* qbase = &Qb[(size_t)bh * L_SEQ * DQ];

  // K fragments for this wave's 16 keys
  const unsigned short* kp0 =
      &Kb[((size_t)bh * L_SEQ + kc * 64 + wave * 16 + col) * DQ];
  short8 kA0 = *(const short8*)&kp0[quad * 8];
  short8 kA1 = *(const short8*)&kp0[32 + quad * 8];

  {  // stage invz for this bh (visible after first in-loop barrier)
    const float4 v = *(const float4*)&invz[(size_t)bh * L_SEQ + tid * 4];
    *(float4*)&izs[tid * 4] = v;
  }

  const int sr = tid >> 2;
  const int so = (tid & 3) * 16;

  float acc[4] = {0.f, 0.f, 0.f, 0.f};

  short8 st0, st1;
  {  // prefetch tile 0
    const unsigned short* s8 = qbase + (size_t)sr * DQ + so;
    st0 = *(const short8*)s8;
    st1 = *(const short8*)(s8 + 8);
  }

#pragma unroll 2
  for (int qt = 0; qt < 16; ++qt) {
    const int buf = qt & 1;
    *(short8*)&Qs[buf][sr][so] = st0;
    *(short8*)&Qs[buf][sr][so + 8] = st1;
    __syncthreads();
    if (qt + 1 < 16) {  // post-barrier prefetch
      const unsigned short* s8 =
          qbase + ((size_t)((qt + 1) * 64 + sr)) * DQ + so;
      st0 = *(const short8*)s8;
      st1 = *(const short8*)(s8 + 8);
    }
#pragma unroll
    for (int sub = 0; sub < 4; ++sub) {
      const unsigned short* qp = &Qs[buf][sub * 16 + col][0];
      short8 qb0 = *(const short8*)&qp[quad * 8];
      short8 qb1 = *(const short8*)&qp[32 + quad * 8];
      const float ivzv = izs[qt * 64 + sub * 16 + col];
      f32x4 s = {0.f, 0.f, 0.f, 0.f};
      s = __builtin_amdgcn_mfma_f32_16x16x32_bf16(kA0, qb0, s, 0, 0, 0);
      s = __builtin_amdgcn_mfma_f32_16x16x32_bf16(kA1, qb1, s, 0, 0, 0);
#pragma unroll
      for (int r = 0; r < 4; ++r)
        acc[r] = fmaf(__builtin_amdgcn_exp2f(s[r]), ivzv, acc[r]);
    }
  }
  // butterfly over the 16 query-lanes; lane col==r holds key quad*4+r
#pragma unroll
  for (int r = 0; r < 4; ++r) {
    float a = acc[r];
#pragma unroll
    for (int off = 1; off <= 8; off <<= 1) a += __shfl_xor(a, off, 64);
    if (col == r) aws[wave * 16 + quad * 4 + r] = a;
  }
  __syncthreads();

  // local V-combine over this block's 64 keys
  const int d = tid & 63, sub4 = tid >> 6;  // 4 subs x 16 keys
  float oacc = 0.f;
#pragma unroll 8
  for (int mm = 0; mm < 16; ++mm) {
    const int m = sub4 * 16 + mm;
    __hip_bfloat16 v;
    *(unsigned short*)&v =
        Vb[((size_t)bh * L_SEQ + kc * 64 + m) * DQ + d];
    oacc = fmaf(aws[m], __bfloat162float(v), oacc);
  }
  red[sub4][d] = oacc;
  __syncthreads();
  if (tid < 64) {
    float p = red[0][tid] + red[1][tid] + red[2][tid] + red[3][tid];
    atomicAdd(&Oacc[(size_t)bh * 64 + tid], p);
  }
  if (tid == 0) {
    __threadfence();                      // release: O adds visible first
    lastFlag = (atomicAdd(&cnt[bh], 1) == 15);
  }
  __syncthreads();
  if (lastFlag && tid < 64) {
    __threadfence();                      // acquire
    float v = atomicAdd(&Oacc[(size_t)bh * 64 + tid], 0.f);
    float s = v;
#pragma unroll
    for (int off = 32; off >= 1; off >>= 1) s += __shfl_xor(s, off, 64);
    float mean = s * (1.f / 64.f);
    float diff = v - mean;
    float sq = diff * diff;
#pragma unroll
    for (int off = 32; off >= 1; off >>= 1) sq += __shfl_xor(sq, off, 64);
    float var = sq * (1.f / 64.f);
    float o = diff * rsqrtf(var + 1e-5f);
    const int b = bh >> 3, h = bh & 7;
    out[(size_t)b * 512 + h * 64 + tid] = o * gnw[h] + gnb[h];
  }
}

extern "C" void kernel_launch(void* const* d_in, const int* in_sizes, int n_in,
                              void* d_out, int out_size, void* d_ws,
                              size_t ws_size, hipStream_t stream) {
  (void)in_sizes; (void)n_in; (void)out_size; (void)ws_size;
  const float* emb  = (const float*)d_in[0];
  const float* W    = (const float*)d_in[1];
  const float* bias = (const float*)d_in[2];
  const float* gnw  = (const float*)d_in[3];
  const float* gnb  = (const float*)d_in[4];
  float* out = (float*)d_out;

  char* ws = (char*)d_ws;
  const size_t perQ = (size_t)BH * L_SEQ * DQ;        // 4,194,304 elems
  unsigned short* embB = (unsigned short*)ws;                      // 8 MB
  unsigned short* WB   = (unsigned short*)(ws + 8u * 1024 * 1024); // 1.5 MB
  unsigned short* Qb   = (unsigned short*)(ws + 10u * 1024 * 1024);
  unsigned short* Kb   = Qb + perQ;   // @18M
  unsigned short* Vb   = Kb + perQ;   // @26M
  float* invz = (float*)(ws + 34u * 1024 * 1024);     // 256 KB
  float* Oacc = (float*)(ws + 35u * 1024 * 1024);     // 16 KB
  int*   cnt  = (int*)(ws + 35u * 1024 * 1024 + 64u * 1024);

  to_bf16<<<dim3(2432), 256, 0, stream>>>(emb, W, embB, WB);
  qkv_mfma<<<dim3(NQKV / 128, 8192 / 128), 256, 0, stream>>>(
      embB, WB, bias, Qb, Kb, Vb);
  attn_z<<<dim3(1024), 256, 0, stream>>>(Qb, Kb, invz, Oacc, cnt);
  attn_aw<<<dim3(1024), 256, 0, stream>>>(Qb, Kb, Vb, invz, gnw, gnb,
                                          Oacc, cnt, out);
}

// Round 11
// 135.845 us; speedup vs baseline: 1.0922x; 1.0922x over previous
//
#include <hip/hip_runtime.h>
#include <hip/hip_bf16.h>
#include <math.h>

#define L_SEQ 1024
#define BSZ 8
#define EMB 512
#define NH 8
#define DQ 64
#define BH 64          // BSZ*NH
#define NQKV 1536      // 3*NH*DQ

// Q is pre-scaled by (emb_dim/n_head)^-0.5 * log2(e) so that
// softmax numerator = exp2(mfma_score) with zero extra VALU per element.
#define SCALE_Q 0.18033688f

typedef __attribute__((ext_vector_type(8))) short short8;   // 8 bf16 = 4 VGPR
typedef __attribute__((ext_vector_type(4))) float f32x4;

#define GPTR(x) ((const __attribute__((address_space(1))) void*)(x))
#define LPTR(x) ((__attribute__((address_space(3))) void*)(x))

__device__ __forceinline__ unsigned short bf16u(float x) {
  __hip_bfloat16 h = __float2bfloat16(x);
  return *(unsigned short*)&h;
}

// ---------------------------------------------------------------------------
// Kernel 0: f32 -> bf16 convert of emb (8192x512) and W (1536x512).
// ---------------------------------------------------------------------------
__global__ __launch_bounds__(256) void to_bf16(
    const float* __restrict__ emb, const float* __restrict__ W,
    unsigned short* __restrict__ embB, unsigned short* __restrict__ WB) {
  const size_t t = (size_t)blockIdx.x * 256 + threadIdx.x;
  size_t base = t * 8;
  const float* src;
  unsigned short* dst;
  size_t off;
  if (base < (size_t)8192 * 512) { src = emb; dst = embB; off = base; }
  else { src = W; dst = WB; off = base - (size_t)8192 * 512; }
  float4 v0 = *(const float4*)&src[off];
  float4 v1 = *(const float4*)&src[off + 4];
  short8 o;
  o[0] = bf16u(v0.x); o[1] = bf16u(v0.y); o[2] = bf16u(v0.z); o[3] = bf16u(v0.w);
  o[4] = bf16u(v1.x); o[5] = bf16u(v1.y); o[6] = bf16u(v1.z); o[7] = bf16u(v1.w);
  *(short8*)&dst[off] = o;
}

// ---------------------------------------------------------------------------
// Kernel A: QKV projection, bf16 MFMA (m97 pattern). Q gets SCALE_Q folded in.
// Epilogue: C-tile staged to LDS (Cs[128][132] bf16), then each 64-col
// half-tile is a contiguous [bh][l][0..63] run -> short8 coalesced stores.
// ---------------------------------------------------------------------------
__global__ __launch_bounds__(256) void qkv_mfma(
    const unsigned short* __restrict__ A,   // embB [8192][512]
    const unsigned short* __restrict__ B,   // WB   [1536][512]
    const float* __restrict__ bias,
    unsigned short* __restrict__ Qb, unsigned short* __restrict__ Kb,
    unsigned short* __restrict__ Vb) {
  __shared__ __align__(16) unsigned short As[128][32];  // 8 KB, unpadded
  __shared__ __align__(16) unsigned short Bs[128][32];  // 8 KB
  __shared__ __align__(16) unsigned short Cs[128][132]; // 33 KB, +4 pad
  const int tid = threadIdx.x;
  const int wave = tid >> 6, lane = tid & 63;
  const int quad = lane >> 4, col = lane & 15;
  const int wr = wave >> 1, wc = wave & 1;
  const int m0 = blockIdx.y * 128, n0 = blockIdx.x * 128;
  const int r16 = lane >> 2, q4 = lane & 3;

  f32x4 acc[4][4] = {};

  for (int kt = 0; kt < EMB; kt += 32) {
    __syncthreads();
#pragma unroll
    for (int c = 0; c < 2; ++c) {
      const int rowA = (c * 4 + wave) * 16;
      __builtin_amdgcn_global_load_lds(
          GPTR(A + (size_t)(m0 + rowA + r16) * EMB + kt + q4 * 8),
          LPTR(&As[rowA][0]), 16, 0, 0);
      __builtin_amdgcn_global_load_lds(
          GPTR(B + (size_t)(n0 + rowA + r16) * EMB + kt + q4 * 8),
          LPTR(&Bs[rowA][0]), 16, 0, 0);
    }
    __syncthreads();
    short8 af[4], bf[4];
#pragma unroll
    for (int i = 0; i < 4; ++i)
      af[i] = *(const short8*)&As[wr * 64 + i * 16 + col][quad * 8];
#pragma unroll
    for (int j = 0; j < 4; ++j)
      bf[j] = *(const short8*)&Bs[wc * 64 + j * 16 + col][quad * 8];
#pragma unroll
    for (int i = 0; i < 4; ++i)
#pragma unroll
      for (int j = 0; j < 4; ++j)
        acc[i][j] =
            __builtin_amdgcn_mfma_f32_16x16x32_bf16(af[i], bf[j], acc[i][j],
                                                    0, 0, 0);
  }

#pragma unroll
  for (int j = 0; j < 4; ++j) {
    const int n = wc * 64 + j * 16 + col;     // tile col 0..127
    const float bj = bias[n0 + n];
    const bool isQ = (((n0 + n) >> 6) % 3) == 0;
#pragma unroll
    for (int i = 0; i < 4; ++i) {
      const int mrow = wr * 64 + i * 16 + quad * 4;
#pragma unroll
      for (int r = 0; r < 4; ++r) {
        float val = acc[i][j][r] + bj;
        if (isQ) val *= SCALE_Q;
        Cs[mrow + r][n] = bf16u(val);
      }
    }
  }
  __syncthreads();
  const int bb = lane >> 3, oct = lane & 7;
#pragma unroll
  for (int e = 0; e < 8; ++e) {
    const int idx = wave * 8 + e;
    const int half = idx >> 4, l = idx & 15;
    const int G = (n0 >> 6) + half;       // 64-col block id, 0..23
    const int h = G / 3, sel = G % 3;
    unsigned short* dst = (sel == 0) ? Qb : (sel == 1) ? Kb : Vb;
    short8 v = *(const short8*)&Cs[l * 8 + bb][half * 64 + oct * 8];
    const int lglob = (m0 >> 3) + l;
    *(short8*)&dst[(((size_t)(bb * NH + h)) * L_SEQ + lglob) * DQ + oct * 8] = v;
  }
}

// ---------------------------------------------------------------------------
// Kernel B1: invz[bh][l] = 1 / sum_m exp2(s_lm).
// v5: 512-thread blocks (8 waves), grid 512 = (bh = blk&63, qc = blk>>6 in
// 0..7), 128 q-rows per block, wave owns 16 rows. Same stream traffic as R9
// (8 blocks/bh; R10 showed 16 blocks/bh doubles L2 traffic = regression) at
// DOUBLE the waves/CU (16) for latency hiding. Double-buffered LDS, prefetch
// AFTER the barrier (loads in flight through compute, consumed at next
// iter's LDS write; dbuf makes the overwrite race-free via barrier kt+1).
// Also zero-inits Oacc/cnt for attn_aw.
// ---------------------------------------------------------------------------
__global__ __launch_bounds__(512) void attn_z(
    const unsigned short* __restrict__ Qb, const unsigned short* __restrict__ Kb,
    float* __restrict__ invz, float* __restrict__ Oacc, int* __restrict__ cnt) {
  const int bh = blockIdx.x & 63;   // blk%8 = bh%8 -> same-bh blocks same XCD
  const int qc = blockIdx.x >> 6;   // 0..7, 128 rows each
  const int tid = threadIdx.x;
  const int wave = tid >> 6, lane = tid & 63;
  const int quad = lane >> 4, col = lane & 15;

  __shared__ __align__(16) unsigned short Ks[2][64][72];  // 18 KB

  if (qc == 0) {
    if (tid < 64) Oacc[(size_t)bh * 64 + tid] = 0.f;
    if (tid == 0) cnt[bh] = 0;
  }

  const unsigned short* kbase = &Kb[(size_t)bh * L_SEQ * DQ];

  // Q fragments for this wave's 16 rows
  const unsigned short* qp =
      &Qb[((size_t)bh * L_SEQ + qc * 128 + wave * 16 + col) * DQ];
  short8 qa0 = *(const short8*)&qp[quad * 8];
  short8 qa1 = *(const short8*)&qp[32 + quad * 8];

  const int sr = tid >> 3;        // staging row 0..63
  const int so = (tid & 7) * 8;   // staging col offset (shorts), 16B each

  float zacc[4] = {0.f, 0.f, 0.f, 0.f};

  short8 st0;
  {  // prefetch tile 0 (one short8 per thread at 512 threads)
    st0 = *(const short8*)(kbase + (size_t)sr * DQ + so);
  }

#pragma unroll 2
  for (int kt = 0; kt < 16; ++kt) {
    const int buf = kt & 1;
    *(short8*)&Ks[buf][sr][so] = st0;
    __syncthreads();
    if (kt + 1 < 16) {  // post-barrier prefetch: in flight through compute
      st0 = *(const short8*)(kbase + ((size_t)((kt + 1) * 64 + sr)) * DQ + so);
    }
#pragma unroll
    for (int sub = 0; sub < 4; ++sub) {
      const unsigned short* kp = &Ks[buf][sub * 16 + col][0];
      short8 kb0 = *(const short8*)&kp[quad * 8];
      short8 kb1 = *(const short8*)&kp[32 + quad * 8];
      f32x4 s = {0.f, 0.f, 0.f, 0.f};
      s = __builtin_amdgcn_mfma_f32_16x16x32_bf16(qa0, kb0, s, 0, 0, 0);
      s = __builtin_amdgcn_mfma_f32_16x16x32_bf16(qa1, kb1, s, 0, 0, 0);
#pragma unroll
      for (int j = 0; j < 4; ++j) zacc[j] += __builtin_amdgcn_exp2f(s[j]);
    }
  }
  float* dst = &invz[(size_t)bh * L_SEQ + qc * 128];
#pragma unroll
  for (int j = 0; j < 4; ++j) {
    float z = zacc[j];
#pragma unroll
    for (int off = 1; off <= 8; off <<= 1) z += __shfl_xor(z, off, 64);
    if (col == j)
      dst[wave * 16 + quad * 4 + j] = __builtin_amdgcn_rcpf(z);
  }
}

// ---------------------------------------------------------------------------
// Kernel B2 (fused): 512-thread blocks, grid 512 = (bh, kc in 0..7), 128
// keys per block, wave owns 16 keys (K rows as A-operand). Q tiles
// double-buffered with post-barrier prefetch. After the sweep: aw for this
// block's 128 keys -> LDS, local V-combine (disjoint 16 KB of V), atomicAdd
// into Oacc[bh], 8th block per bh does GroupNorm + out (G16-safe:
// device-scope atomics + threadfence release/acquire).
// ---------------------------------------------------------------------------
__global__ __launch_bounds__(512) void attn_aw(
    const unsigned short* __restrict__ Qb, const unsigned short* __restrict__ Kb,
    const unsigned short* __restrict__ Vb, const float* __restrict__ invz,
    const float* __restrict__ gnw, const float* __restrict__ gnb,
    float* __restrict__ Oacc, int* __restrict__ cnt, float* __restrict__ out) {
  const int bh = blockIdx.x & 63;
  const int kc = blockIdx.x >> 6;   // 0..7, 128 keys each
  const int tid = threadIdx.x;
  const int wave = tid >> 6, lane = tid & 63;
  const int quad = lane >> 4, col = lane & 15;

  __shared__ __align__(16) unsigned short Qs[2][64][72];  // 18 KB
  __shared__ float izs[1024];                             // 4 KB
  __shared__ float aws[128];
  __shared__ float red[8][64];
  __shared__ int lastFlag;

  const unsigned short* qbase = &Qb[(size_t)bh * L_SEQ * DQ];

  // K fragments for this wave's 16 keys
  const unsigned short* kp0 =
      &Kb[((size_t)bh * L_SEQ + kc * 128 + wave * 16 + col) * DQ];
  short8 kA0 = *(const short8*)&kp0[quad * 8];
  short8 kA1 = *(const short8*)&kp0[32 + quad * 8];

  {  // stage invz for this bh (visible after first in-loop barrier)
    const float2 v = *(const float2*)&invz[(size_t)bh * L_SEQ + tid * 2];
    *(float2*)&izs[tid * 2] = v;
  }

  const int sr = tid >> 3;
  const int so = (tid & 7) * 8;

  float acc[4] = {0.f, 0.f, 0.f, 0.f};

  short8 st0;
  {  // prefetch tile 0
    st0 = *(const short8*)(qbase + (size_t)sr * DQ + so);
  }

#pragma unroll 2
  for (int qt = 0; qt < 16; ++qt) {
    const int buf = qt & 1;
    *(short8*)&Qs[buf][sr][so] = st0;
    __syncthreads();
    if (qt + 1 < 16) {  // post-barrier prefetch
      st0 = *(const short8*)(qbase + ((size_t)((qt + 1) * 64 + sr)) * DQ + so);
    }
#pragma unroll
    for (int sub = 0; sub < 4; ++sub) {
      const unsigned short* qp = &Qs[buf][sub * 16 + col][0];
      short8 qb0 = *(const short8*)&qp[quad * 8];
      short8 qb1 = *(const short8*)&qp[32 + quad * 8];
      const float ivzv = izs[qt * 64 + sub * 16 + col];
      f32x4 s = {0.f, 0.f, 0.f, 0.f};
      s = __builtin_amdgcn_mfma_f32_16x16x32_bf16(kA0, qb0, s, 0, 0, 0);
      s = __builtin_amdgcn_mfma_f32_16x16x32_bf16(kA1, qb1, s, 0, 0, 0);
#pragma unroll
      for (int r = 0; r < 4; ++r)
        acc[r] = fmaf(__builtin_amdgcn_exp2f(s[r]), ivzv, acc[r]);
    }
  }
  // butterfly over the 16 query-lanes; lane col==r holds key quad*4+r
#pragma unroll
  for (int r = 0; r < 4; ++r) {
    float a = acc[r];
#pragma unroll
    for (int off = 1; off <= 8; off <<= 1) a += __shfl_xor(a, off, 64);
    if (col == r) aws[wave * 16 + quad * 4 + r] = a;
  }
  __syncthreads();

  // local V-combine over this block's 128 keys (8 subs x 16 keys)
  const int d = tid & 63, sub8 = tid >> 6;
  float oacc = 0.f;
#pragma unroll 8
  for (int mm = 0; mm < 16; ++mm) {
    const int m = sub8 * 16 + mm;
    __hip_bfloat16 v;
    *(unsigned short*)&v =
        Vb[((size_t)bh * L_SEQ + kc * 128 + m) * DQ + d];
    oacc = fmaf(aws[m], __bfloat162float(v), oacc);
  }
  red[sub8][d] = oacc;
  __syncthreads();
  if (tid < 64) {
    float p = red[0][tid] + red[1][tid] + red[2][tid] + red[3][tid] +
              red[4][tid] + red[5][tid] + red[6][tid] + red[7][tid];
    atomicAdd(&Oacc[(size_t)bh * 64 + tid], p);
  }
  if (tid == 0) {
    __threadfence();                      // release: O adds visible first
    lastFlag = (atomicAdd(&cnt[bh], 1) == 7);
  }
  __syncthreads();
  if (lastFlag && tid < 64) {
    __threadfence();                      // acquire
    float v = atomicAdd(&Oacc[(size_t)bh * 64 + tid], 0.f);
    float s = v;
#pragma unroll
    for (int off = 32; off >= 1; off >>= 1) s += __shfl_xor(s, off, 64);
    float mean = s * (1.f / 64.f);
    float diff = v - mean;
    float sq = diff * diff;
#pragma unroll
    for (int off = 32; off >= 1; off >>= 1) sq += __shfl_xor(sq, off, 64);
    float var = sq * (1.f / 64.f);
    float o = diff * rsqrtf(var + 1e-5f);
    const int b = bh >> 3, h = bh & 7;
    out[(size_t)b * 512 + h * 64 + tid] = o * gnw[h] + gnb[h];
  }
}

extern "C" void kernel_launch(void* const* d_in, const int* in_sizes, int n_in,
                              void* d_out, int out_size, void* d_ws,
                              size_t ws_size, hipStream_t stream) {
  (void)in_sizes; (void)n_in; (void)out_size; (void)ws_size;
  const float* emb  = (const float*)d_in[0];
  const float* W    = (const float*)d_in[1];
  const float* bias = (const float*)d_in[2];
  const float* gnw  = (const float*)d_in[3];
  const float* gnb  = (const float*)d_in[4];
  float* out = (float*)d_out;

  char* ws = (char*)d_ws;
  const size_t perQ = (size_t)BH * L_SEQ * DQ;        // 4,194,304 elems
  unsigned short* embB = (unsigned short*)ws;                      // 8 MB
  unsigned short* WB   = (unsigned short*)(ws + 8u * 1024 * 1024); // 1.5 MB
  unsigned short* Qb   = (unsigned short*)(ws + 10u * 1024 * 1024);
  unsigned short* Kb   = Qb + perQ;   // @18M
  unsigned short* Vb   = Kb + perQ;   // @26M
  float* invz = (float*)(ws + 34u * 1024 * 1024);     // 256 KB
  float* Oacc = (float*)(ws + 35u * 1024 * 1024);     // 16 KB
  int*   cnt  = (int*)(ws + 35u * 1024 * 1024 + 64u * 1024);

  to_bf16<<<dim3(2432), 256, 0, stream>>>(emb, W, embB, WB);
  qkv_mfma<<<dim3(NQKV / 128, 8192 / 128), 256, 0, stream>>>(
      embB, WB, bias, Qb, Kb, Vb);
  attn_z<<<dim3(512), 512, 0, stream>>>(Qb, Kb, invz, Oacc, cnt);
  attn_aw<<<dim3(512), 512, 0, stream>>>(Qb, Kb, Vb, invz, gnw, gnb,
                                         Oacc, cnt, out);
}